// Round 5
// baseline (882.729 us; speedup 1.0000x reference)
//
#include <hip/hip_runtime.h>
#include <stdint.h>

// Problem constants
#define T_  512
#define V_  512
#define F_  12
#define FP_ 16
#define D_  512
#define H_  8
#define HF_ 96

using half8  = __attribute__((ext_vector_type(8))) _Float16;
using f32x4  = __attribute__((ext_vector_type(4))) float;
using uint4v = __attribute__((ext_vector_type(4))) unsigned int;
using uint2v = __attribute__((ext_vector_type(2))) unsigned int;

// Workspace layout (bytes). Used total = ~27.3 MB
#define OFF_TB   (0L)                       // text fp16      [512][512]
#define OFF_VB   (524288L)                  // video fp16     [512][16][512] (F padded, zeros)
#define OFF_WQT  (OFF_VB  + 8388608L)       // WqT fp16       [512][512]  WqT[n][k]=Wq[k][n]
#define OFF_WKT  (OFF_WQT + 524288L)
#define OFF_WVT  (OFF_WKT + 524288L)
#define OFF_WOT  (OFF_WVT + 524288L)
#define OFF_QB   (OFF_WOT + 524288L)        // q fp16 (x0.125)[512][512]
#define OFF_KP   (OFF_QB  + 524288L)        // kproj fp16     [512][16][512]
#define OFF_VP   (OFF_KP  + 8388608L)       // vproj fp16     [512][16][512]

__device__ __forceinline__ unsigned short f2h(float x) {
  _Float16 h = (_Float16)x;
  return __builtin_bit_cast(unsigned short, h);
}

__device__ __forceinline__ void cvt8_store(float4 a, float4 b, unsigned short* dst) {
  unsigned int w0 = f2h(a.x) | ((unsigned int)f2h(a.y) << 16);
  unsigned int w1 = f2h(a.z) | ((unsigned int)f2h(a.w) << 16);
  unsigned int w2 = f2h(b.x) | ((unsigned int)f2h(b.y) << 16);
  unsigned int w3 = f2h(b.z) | ((unsigned int)f2h(b.w) << 16);
  uint4v v = {w0, w1, w2, w3};
  *(uint4v*)dst = v;
}

// ---------------------------------------------------------------------------
// K0: convert inputs to fp16; build transposed fp16 weight copies.
// grid: [0,128) text | [128,2176) video (padded F=16) | [2176,2432) transposes
// ---------------------------------------------------------------------------
__global__ __launch_bounds__(256) void k0_prep(
    const float* __restrict__ text, const float* __restrict__ video,
    const float* __restrict__ Wq, const float* __restrict__ Wk,
    const float* __restrict__ Wv, const float* __restrict__ Wo, char* ws) {
  __shared__ unsigned short tl[64][72];
  int bx = blockIdx.x, tid = threadIdx.x;
  if (bx < 128) {
    unsigned short* tb = (unsigned short*)(ws + OFF_TB);
    long i = ((long)bx * 256 + tid) * 8;
    float4 a = *(const float4*)(text + i);
    float4 b = *(const float4*)(text + i + 4);
    cvt8_store(a, b, tb + i);
  } else if (bx < 2176) {
    unsigned short* vb = (unsigned short*)(ws + OFF_VB);
    long j = ((long)(bx - 128) * 256 + tid) * 8;  // elem idx in [512][16][512]
    int row = (int)(j >> 9);
    int c   = (int)(j & 511);
    int f = row & 15, v = row >> 4;
    if (f < F_) {
      const float* src = video + ((long)(v * F_ + f) << 9) + c;
      float4 a = *(const float4*)src;
      float4 b = *(const float4*)(src + 4);
      cvt8_store(a, b, vb + j);
    } else {
      uint4v z = {0, 0, 0, 0};
      *(uint4v*)(vb + j) = z;
    }
  } else {
    int tix = bx - 2176;
    int w = tix >> 6, tile = tix & 63;
    const float* W = (w == 0) ? Wq : (w == 1) ? Wk : (w == 2) ? Wv : Wo;
    unsigned short* WT = (unsigned short*)(ws +
        ((w == 0) ? OFF_WQT : (w == 1) ? OFF_WKT : (w == 2) ? OFF_WVT : OFF_WOT));
    int r0 = (tile >> 3) * 64, c0 = (tile & 7) * 64;
    int rr = tid >> 4, cc = (tid & 15) * 4;
#pragma unroll
    for (int j2 = 0; j2 < 4; ++j2) {
      int r = rr + j2 * 16;
      float4 a = *(const float4*)(W + (long)(r0 + r) * 512 + c0 + cc);
      tl[cc + 0][r] = f2h(a.x);
      tl[cc + 1][r] = f2h(a.y);
      tl[cc + 2][r] = f2h(a.z);
      tl[cc + 3][r] = f2h(a.w);
    }
    __syncthreads();
    // 256 threads x 16 ushorts = the full 64x64 tile in ONE pass.
    int row_l = tid >> 2, u = (tid & 3) * 16;
    uint4v x0 = *(uint4v*)&tl[row_l][u];
    uint4v x1 = *(uint4v*)&tl[row_l][u + 8];
    unsigned short* dst = WT + (long)(c0 + row_l) * 512 + r0 + u;
    *(uint4v*)dst = x0;
    *(uint4v*)(dst + 8) = x1;
  }
}

// ---------------------------------------------------------------------------
// K1: fused projection GEMMs (fp16 MFMA).  out = (A @ W + b) * scale
// grid = 132 mtiles * 4 ntiles; seg mt<4: q | mt<68: kproj | else: vproj
// tile 128x128, BK=64, 4 waves (2x2 of 64x64)
// ---------------------------------------------------------------------------
__global__ __launch_bounds__(256) void k1_proj(
    char* ws, const float* __restrict__ bq, const float* __restrict__ bk,
    const float* __restrict__ bv) {
  __shared__ unsigned short As[128 * 72];
  __shared__ unsigned short Bs[128 * 72];
  int bx = blockIdx.x, tid = threadIdx.x;
  int nt = bx & 3, mt = bx >> 2;
  const unsigned short* A;
  const unsigned short* BT;
  const float* bias;
  float scale;
  unsigned short* out;
  int m0;
  if (mt < 4) {
    A = (const unsigned short*)(ws + OFF_TB);
    BT = (const unsigned short*)(ws + OFF_WQT);
    bias = bq; scale = 0.125f;
    out = (unsigned short*)(ws + OFF_QB);
    m0 = mt << 7;
  } else if (mt < 68) {
    A = (const unsigned short*)(ws + OFF_VB);
    BT = (const unsigned short*)(ws + OFF_WKT);
    bias = bk; scale = 1.0f;
    out = (unsigned short*)(ws + OFF_KP);
    m0 = (mt - 4) << 7;
  } else {
    A = (const unsigned short*)(ws + OFF_VB);
    BT = (const unsigned short*)(ws + OFF_WVT);
    bias = bv; scale = 1.0f;
    out = (unsigned short*)(ws + OFF_VP);
    m0 = (mt - 68) << 7;
  }
  int n0 = nt << 7;
  int lane = tid & 63, wid = tid >> 6;
  int mw = (wid >> 1) << 6, nw = (wid & 1) << 6;
  int l15 = lane & 15, g = lane >> 4;
  f32x4 acc[4][4];
#pragma unroll
  for (int i = 0; i < 4; i++)
#pragma unroll
    for (int j = 0; j < 4; j++) acc[i][j] = (f32x4){0.f, 0.f, 0.f, 0.f};

  for (int ks = 0; ks < 8; ++ks) {
    __syncthreads();
    // stage A,B [128][64] -> padded [128][72]
#pragma unroll
    for (int j = 0; j < 4; ++j) {
      int flat = (j * 256 + tid) * 8;
      int row = flat >> 6, col = flat & 63;
      uint4v va = *(const uint4v*)(A + (long)(m0 + row) * 512 + ks * 64 + col);
      uint4v vb = *(const uint4v*)(BT + (long)(n0 + row) * 512 + ks * 64 + col);
      *(uint4v*)(As + row * 72 + col) = va;
      *(uint4v*)(Bs + row * 72 + col) = vb;
    }
    __syncthreads();
#pragma unroll
    for (int k2 = 0; k2 < 2; ++k2) {
      half8 a[4], b[4];
#pragma unroll
      for (int i = 0; i < 4; i++) {
        a[i] = *(const half8*)(As + (mw + i * 16 + l15) * 72 + k2 * 32 + (g << 3));
        b[i] = *(const half8*)(Bs + (nw + i * 16 + l15) * 72 + k2 * 32 + (g << 3));
      }
#pragma unroll
      for (int i = 0; i < 4; i++)
#pragma unroll
        for (int j = 0; j < 4; j++)
          acc[i][j] = __builtin_amdgcn_mfma_f32_16x16x32_f16(a[i], b[j], acc[i][j], 0, 0, 0);
    }
  }
#pragma unroll
  for (int j = 0; j < 4; j++) {
    int n = n0 + nw + j * 16 + l15;
    float bsv = bias[n];
#pragma unroll
    for (int i = 0; i < 4; i++) {
      int rbase = m0 + mw + i * 16 + (g << 2);
#pragma unroll
      for (int r = 0; r < 4; r++) {
        float x = (acc[i][j][r] + bsv) * scale;
        out[(long)(rbase + r) * 512 + n] = f2h(x);
      }
    }
  }
}

// ---------------------------------------------------------------------------
// K5: fused logits+softmax (P), Wo-contraction (Z), and output GEMM.
// Block = (v, tt, nt): 128t x 128n output tile, 4 waves (2x2 of 64x64).
//
// P prologue (per wave, 32 t rows):  D[f][t] = mfma(A=kproj rows f, B=q rows t)
//   -> lane(l15=t, g) reg r holds logit[f=g*4+r][t]; frame-sum = 3 adds +
//      shfl_xor(16)+shfl_xor(32); no max-subtract (|logit| <~ 6, fp32-safe);
//      P -> As[t][h*12+f] via one ds_write_b64 (g<3).
// Z prologue (per wave, 32 n rows):  D[f][n] = mfma(A=vproj rows f, B=WoT rows n)
//   -> Bs[n][h*12+f] via ds_write_b64 (g<3).
// Main: out[t][n] = sum_{hf} As[t][hf]*Bs[n][hf], 3 K-steps of 32, +bo.
// Padded f rows (12..15) of kproj/vproj hold bias values (finite) and are
// never written (g==3 skipped) — same masking as the verified K2/K3.
// XCD swizzle: 8192 blocks % 8 == 0 -> bijective; all 16 blocks of a v share
// one XCD's L2 (kp[v], vp[v], q, WOT become L2-resident).
// ---------------------------------------------------------------------------
__global__ __launch_bounds__(256) void k5_fused(char* ws, const float* __restrict__ bo,
                                                float* __restrict__ outp) {
  __shared__ unsigned short As[128 * 104];  // P tile [t][96(+8 pad)]
  __shared__ unsigned short Bs[128 * 104];  // Z tile [n][96(+8 pad)]
  int bx = blockIdx.x, tid = threadIdx.x;
  int bsw = (bx & 7) * 1024 + (bx >> 3);    // XCD-contiguous remap
  int v = bsw >> 4, tt = (bsw >> 2) & 3, nt = bsw & 3;

  const unsigned short* QB = (const unsigned short*)(ws + OFF_QB);
  const unsigned short* KP = (const unsigned short*)(ws + OFF_KP);
  const unsigned short* VP = (const unsigned short*)(ws + OFF_VP);
  const unsigned short* WOT = (const unsigned short*)(ws + OFF_WOT);

  int lane = tid & 63, wid = tid >> 6;
  int l15 = lane & 15, g = lane >> 4;

  // ---- P prologue: wave covers t rows [tt*128 + wid*32, +32) ----
  {
    const unsigned short* kpr = KP + ((long)(v * 16 + l15) << 9);  // A row f=l15
#pragma unroll
    for (int h = 0; h < H_; ++h) {
      half8 a0 = *(const half8*)(kpr + h * 64 + (g << 3));
      half8 a1 = *(const half8*)(kpr + h * 64 + 32 + (g << 3));
#pragma unroll
      for (int ti = 0; ti < 2; ++ti) {
        int tl = (wid << 5) + (ti << 4);               // local t base
        const unsigned short* qr = QB + ((long)(tt * 128 + tl + l15) << 9);
        half8 b0 = *(const half8*)(qr + h * 64 + (g << 3));
        half8 b1 = *(const half8*)(qr + h * 64 + 32 + (g << 3));
        f32x4 acc = {0.f, 0.f, 0.f, 0.f};
        acc = __builtin_amdgcn_mfma_f32_16x16x32_f16(a0, b0, acc, 0, 0, 0);
        acc = __builtin_amdgcn_mfma_f32_16x16x32_f16(a1, b1, acc, 0, 0, 0);
        // softmax over frames, no max-pass (|logit| bounded ~6)
        float e0 = (g < 3) ? __expf(acc[0]) : 0.f;
        float e1 = (g < 3) ? __expf(acc[1]) : 0.f;
        float e2 = (g < 3) ? __expf(acc[2]) : 0.f;
        float e3 = (g < 3) ? __expf(acc[3]) : 0.f;
        float s = e0 + e1 + e2 + e3;
        s += __shfl_xor(s, 16);
        s += __shfl_xor(s, 32);
        float inv = 1.0f / s;
        if (g < 3) {
          unsigned int w0 = f2h(e0 * inv) | ((unsigned int)f2h(e1 * inv) << 16);
          unsigned int w1 = f2h(e2 * inv) | ((unsigned int)f2h(e3 * inv) << 16);
          uint2v pk = {w0, w1};
          *(uint2v*)(As + (tl + l15) * 104 + h * 12 + (g << 2)) = pk;
        }
      }
    }
  }

  // ---- Z prologue: wave covers n rows [nt*128 + wid*32, +32) ----
  {
    const unsigned short* vpr = VP + ((long)(v * 16 + l15) << 9);  // A row f=l15
#pragma unroll
    for (int h = 0; h < H_; ++h) {
      half8 a0 = *(const half8*)(vpr + h * 64 + (g << 3));
      half8 a1 = *(const half8*)(vpr + h * 64 + 32 + (g << 3));
#pragma unroll
      for (int mf = 0; mf < 2; ++mf) {
        int nl = (wid << 5) + (mf << 4);               // local n base
        const unsigned short* wor = WOT + ((long)(nt * 128 + nl + l15) << 9);
        half8 b0 = *(const half8*)(wor + h * 64 + (g << 3));
        half8 b1 = *(const half8*)(wor + h * 64 + 32 + (g << 3));
        f32x4 acc = {0.f, 0.f, 0.f, 0.f};
        acc = __builtin_amdgcn_mfma_f32_16x16x32_f16(a0, b0, acc, 0, 0, 0);
        acc = __builtin_amdgcn_mfma_f32_16x16x32_f16(a1, b1, acc, 0, 0, 0);
        if (g < 3) {
          unsigned int w0 = f2h(acc[0]) | ((unsigned int)f2h(acc[1]) << 16);
          unsigned int w1 = f2h(acc[2]) | ((unsigned int)f2h(acc[3]) << 16);
          uint2v pk = {w0, w1};
          *(uint2v*)(Bs + (nl + l15) * 104 + h * 12 + (g << 2)) = pk;
        }
      }
    }
  }

  __syncthreads();

  // ---- main GEMM: [128t x 96] x [96 x 128n] ----
  int mw = (wid >> 1) << 6, nw = (wid & 1) << 6;
  f32x4 acc[4][4];
#pragma unroll
  for (int i = 0; i < 4; i++)
#pragma unroll
    for (int j = 0; j < 4; j++) acc[i][j] = (f32x4){0.f, 0.f, 0.f, 0.f};
#pragma unroll
  for (int ks = 0; ks < 3; ++ks) {
    half8 a[4], b[4];
#pragma unroll
    for (int i = 0; i < 4; i++) {
      a[i] = *(const half8*)(As + (mw + i * 16 + l15) * 104 + ks * 32 + (g << 3));
      b[i] = *(const half8*)(Bs + (nw + i * 16 + l15) * 104 + ks * 32 + (g << 3));
    }
#pragma unroll
    for (int i = 0; i < 4; i++)
#pragma unroll
      for (int j = 0; j < 4; j++)
        acc[i][j] = __builtin_amdgcn_mfma_f32_16x16x32_f16(a[i], b[j], acc[i][j], 0, 0, 0);
  }
#pragma unroll
  for (int j = 0; j < 4; j++) {
    int n = (nt << 7) + nw + j * 16 + l15;
    float bias = bo[n];
#pragma unroll
    for (int i = 0; i < 4; i++) {
      long tb_ = (long)(v * 512 + (tt << 7) + mw + i * 16 + (g << 2));
#pragma unroll
      for (int r = 0; r < 4; r++) {
        outp[(tb_ + r) * 512 + n] = acc[i][j][r] + bias;
      }
    }
  }
}

extern "C" void kernel_launch(void* const* d_in, const int* in_sizes, int n_in,
                              void* d_out, int out_size, void* d_ws, size_t ws_size,
                              hipStream_t stream) {
  const float* text  = (const float*)d_in[0];
  const float* video = (const float*)d_in[1];
  const float* Wq = (const float*)d_in[2];
  const float* bq = (const float*)d_in[3];
  const float* Wk = (const float*)d_in[4];
  const float* bk = (const float*)d_in[5];
  const float* Wv = (const float*)d_in[6];
  const float* bv = (const float*)d_in[7];
  const float* Wo = (const float*)d_in[8];
  const float* bo = (const float*)d_in[9];
  char* ws = (char*)d_ws;
  float* out = (float*)d_out;

  k0_prep<<<dim3(2432), dim3(256), 0, stream>>>(text, video, Wq, Wk, Wv, Wo, ws);
  k1_proj<<<dim3(528), dim3(256), 0, stream>>>(ws, bq, bk, bv);
  k5_fused<<<dim3(8192), dim3(256), 0, stream>>>(ws, bo, out);
}

// Round 6
// 837.465 us; speedup vs baseline: 1.0540x; 1.0540x over previous
//
#include <hip/hip_runtime.h>
#include <stdint.h>

// Problem constants
#define T_  512
#define V_  512
#define F_  12
#define FP_ 16
#define D_  512
#define H_  8
#define HF_ 96

using half8  = __attribute__((ext_vector_type(8))) _Float16;
using f32x4  = __attribute__((ext_vector_type(4))) float;
using uint4v = __attribute__((ext_vector_type(4))) unsigned int;
using uint2v = __attribute__((ext_vector_type(2))) unsigned int;

// Workspace layout (bytes). Used total = ~128 MB
#define OFF_TB   (0L)                       // text fp16      [512][512]
#define OFF_VB   (524288L)                  // video fp16     [512][16][512] (F padded, zeros)
#define OFF_WQT  (OFF_VB  + 8388608L)       // WqT fp16       [512][512]  WqT[n][k]=Wq[k][n]
#define OFF_WKT  (OFF_WQT + 524288L)
#define OFF_WVT  (OFF_WKT + 524288L)
#define OFF_WOT  (OFF_WVT + 524288L)
#define OFF_QB   (OFF_WOT + 524288L)        // q fp16 (x0.125)[512][512]
#define OFF_KP   (OFF_QB  + 524288L)        // kproj fp16     [512][16][512]
#define OFF_VP   (OFF_KP  + 8388608L)       // vproj fp16     [512][16][512]
#define OFF_ZT   (OFF_VP  + 8388608L)       // Zt fp16        [512][512][96]  Zt[v][n][h*12+f]
#define OFF_WT   (OFF_ZT  + 50331648L)      // Wt fp16        [512][512][96]  Wt[v][t][h*12+f]

__device__ __forceinline__ unsigned short f2h(float x) {
  _Float16 h = (_Float16)x;
  return __builtin_bit_cast(unsigned short, h);
}

__device__ __forceinline__ void cvt8_store(float4 a, float4 b, unsigned short* dst) {
  unsigned int w0 = f2h(a.x) | ((unsigned int)f2h(a.y) << 16);
  unsigned int w1 = f2h(a.z) | ((unsigned int)f2h(a.w) << 16);
  unsigned int w2 = f2h(b.x) | ((unsigned int)f2h(b.y) << 16);
  unsigned int w3 = f2h(b.z) | ((unsigned int)f2h(b.w) << 16);
  uint4v v = {w0, w1, w2, w3};
  *(uint4v*)dst = v;
}

// ---------------------------------------------------------------------------
// K0: convert inputs to fp16; build transposed fp16 weight copies.
// grid: [0,128) text | [128,2176) video (padded F=16) | [2176,2432) transposes
// ---------------------------------------------------------------------------
__global__ __launch_bounds__(256) void k0_prep(
    const float* __restrict__ text, const float* __restrict__ video,
    const float* __restrict__ Wq, const float* __restrict__ Wk,
    const float* __restrict__ Wv, const float* __restrict__ Wo, char* ws) {
  __shared__ unsigned short tl[64][72];
  int bx = blockIdx.x, tid = threadIdx.x;
  if (bx < 128) {
    unsigned short* tb = (unsigned short*)(ws + OFF_TB);
    long i = ((long)bx * 256 + tid) * 8;
    float4 a = *(const float4*)(text + i);
    float4 b = *(const float4*)(text + i + 4);
    cvt8_store(a, b, tb + i);
  } else if (bx < 2176) {
    unsigned short* vb = (unsigned short*)(ws + OFF_VB);
    long j = ((long)(bx - 128) * 256 + tid) * 8;  // elem idx in [512][16][512]
    int row = (int)(j >> 9);
    int c   = (int)(j & 511);
    int f = row & 15, v = row >> 4;
    if (f < F_) {
      const float* src = video + ((long)(v * F_ + f) << 9) + c;
      float4 a = *(const float4*)src;
      float4 b = *(const float4*)(src + 4);
      cvt8_store(a, b, vb + j);
    } else {
      uint4v z = {0, 0, 0, 0};
      *(uint4v*)(vb + j) = z;
    }
  } else {
    int tix = bx - 2176;
    int w = tix >> 6, tile = tix & 63;
    const float* W = (w == 0) ? Wq : (w == 1) ? Wk : (w == 2) ? Wv : Wo;
    unsigned short* WT = (unsigned short*)(ws +
        ((w == 0) ? OFF_WQT : (w == 1) ? OFF_WKT : (w == 2) ? OFF_WVT : OFF_WOT));
    int r0 = (tile >> 3) * 64, c0 = (tile & 7) * 64;
    int rr = tid >> 4, cc = (tid & 15) * 4;
#pragma unroll
    for (int j2 = 0; j2 < 4; ++j2) {
      int r = rr + j2 * 16;
      float4 a = *(const float4*)(W + (long)(r0 + r) * 512 + c0 + cc);
      tl[cc + 0][r] = f2h(a.x);
      tl[cc + 1][r] = f2h(a.y);
      tl[cc + 2][r] = f2h(a.z);
      tl[cc + 3][r] = f2h(a.w);
    }
    __syncthreads();
    // 256 threads x 16 ushorts = the full 64x64 tile in ONE pass.
    int row_l = tid >> 2, u = (tid & 3) * 16;
    uint4v x0 = *(uint4v*)&tl[row_l][u];
    uint4v x1 = *(uint4v*)&tl[row_l][u + 8];
    unsigned short* dst = WT + (long)(c0 + row_l) * 512 + r0 + u;
    *(uint4v*)dst = x0;
    *(uint4v*)(dst + 8) = x1;
  }
}

// ---------------------------------------------------------------------------
// K1: fused projection GEMMs (fp16 MFMA).  out = (A @ W + b) * scale
// grid = 132 mtiles * 4 ntiles; seg mt<4: q | mt<68: kproj | else: vproj
// tile 128x128, BK=64, 4 waves (2x2 of 64x64)
// ---------------------------------------------------------------------------
__global__ __launch_bounds__(256) void k1_proj(
    char* ws, const float* __restrict__ bq, const float* __restrict__ bk,
    const float* __restrict__ bv) {
  __shared__ unsigned short As[128 * 72];
  __shared__ unsigned short Bs[128 * 72];
  int bx = blockIdx.x, tid = threadIdx.x;
  int nt = bx & 3, mt = bx >> 2;
  const unsigned short* A;
  const unsigned short* BT;
  const float* bias;
  float scale;
  unsigned short* out;
  int m0;
  if (mt < 4) {
    A = (const unsigned short*)(ws + OFF_TB);
    BT = (const unsigned short*)(ws + OFF_WQT);
    bias = bq; scale = 0.125f;
    out = (unsigned short*)(ws + OFF_QB);
    m0 = mt << 7;
  } else if (mt < 68) {
    A = (const unsigned short*)(ws + OFF_VB);
    BT = (const unsigned short*)(ws + OFF_WKT);
    bias = bk; scale = 1.0f;
    out = (unsigned short*)(ws + OFF_KP);
    m0 = (mt - 4) << 7;
  } else {
    A = (const unsigned short*)(ws + OFF_VB);
    BT = (const unsigned short*)(ws + OFF_WVT);
    bias = bv; scale = 1.0f;
    out = (unsigned short*)(ws + OFF_VP);
    m0 = (mt - 68) << 7;
  }
  int n0 = nt << 7;
  int lane = tid & 63, wid = tid >> 6;
  int mw = (wid >> 1) << 6, nw = (wid & 1) << 6;
  int l15 = lane & 15, g = lane >> 4;
  f32x4 acc[4][4];
#pragma unroll
  for (int i = 0; i < 4; i++)
#pragma unroll
    for (int j = 0; j < 4; j++) acc[i][j] = (f32x4){0.f, 0.f, 0.f, 0.f};

  for (int ks = 0; ks < 8; ++ks) {
    __syncthreads();
    // stage A,B [128][64] -> padded [128][72]
#pragma unroll
    for (int j = 0; j < 4; ++j) {
      int flat = (j * 256 + tid) * 8;
      int row = flat >> 6, col = flat & 63;
      uint4v va = *(const uint4v*)(A + (long)(m0 + row) * 512 + ks * 64 + col);
      uint4v vb = *(const uint4v*)(BT + (long)(n0 + row) * 512 + ks * 64 + col);
      *(uint4v*)(As + row * 72 + col) = va;
      *(uint4v*)(Bs + row * 72 + col) = vb;
    }
    __syncthreads();
#pragma unroll
    for (int k2 = 0; k2 < 2; ++k2) {
      half8 a[4], b[4];
#pragma unroll
      for (int i = 0; i < 4; i++) {
        a[i] = *(const half8*)(As + (mw + i * 16 + l15) * 72 + k2 * 32 + (g << 3));
        b[i] = *(const half8*)(Bs + (nw + i * 16 + l15) * 72 + k2 * 32 + (g << 3));
      }
#pragma unroll
      for (int i = 0; i < 4; i++)
#pragma unroll
        for (int j = 0; j < 4; j++)
          acc[i][j] = __builtin_amdgcn_mfma_f32_16x16x32_f16(a[i], b[j], acc[i][j], 0, 0, 0);
    }
  }
#pragma unroll
  for (int j = 0; j < 4; j++) {
    int n = n0 + nw + j * 16 + l15;
    float bsv = bias[n];
#pragma unroll
    for (int i = 0; i < 4; i++) {
      int rbase = m0 + mw + i * 16 + (g << 2);
#pragma unroll
      for (int r = 0; r < 4; r++) {
        float x = (acc[i][j][r] + bsv) * scale;
        out[(long)(rbase + r) * 512 + n] = f2h(x);
      }
    }
  }
}

// ---------------------------------------------------------------------------
// K6: P (softmax weights) and Z (Wo-contraction) to workspace.  NO LDS, NO
// barriers -> high occupancy hides the row-gather L2 latency (round-5 lesson:
// the same math fused behind a barrier at 3 blocks/CU ran latency-bound).
// grid = 4096: bx<2048 -> P-tile (v, 128 t-rows); else Z-tile (v, 128 n-rows).
// Per wave 32 rows; swapped-operand MFMA:
//   P: D[f][t] = mfma(A=kproj f-rows, B=q t-rows); softmax over f in-lane
//      (3 adds + 2 shfl_xor); no max-pass (|logit| <~ 6).
//   Z: D[f][n] = mfma(A=vproj f-rows, B=WoT n-rows).
// Lane(l15,g) reg r holds f=g*4+r; g==3 (padded f=12..15) never stored.
// ---------------------------------------------------------------------------
__global__ __launch_bounds__(256) void k6_pz(char* ws) {
  int bx = blockIdx.x, tid = threadIdx.x;
  int lane = tid & 63, wid = tid >> 6;
  int l15 = lane & 15, g = lane >> 4;
  const unsigned short* QB = (const unsigned short*)(ws + OFF_QB);
  const unsigned short* KP = (const unsigned short*)(ws + OFF_KP);
  const unsigned short* VP = (const unsigned short*)(ws + OFF_VP);
  const unsigned short* WOT = (const unsigned short*)(ws + OFF_WOT);

  if (bx < 2048) {
    int v = bx >> 2, qt = bx & 3;
    unsigned short* Wt = (unsigned short*)(ws + OFF_WT);
    const unsigned short* kpr = KP + ((long)(v * 16 + l15) << 9);  // A row f=l15
#pragma unroll
    for (int h = 0; h < H_; ++h) {
      half8 a0 = *(const half8*)(kpr + h * 64 + (g << 3));
      half8 a1 = *(const half8*)(kpr + h * 64 + 32 + (g << 3));
#pragma unroll
      for (int ti = 0; ti < 2; ++ti) {
        int t = (qt << 7) + (wid << 5) + (ti << 4) + l15;
        const unsigned short* qr = QB + ((long)t << 9);
        half8 b0 = *(const half8*)(qr + h * 64 + (g << 3));
        half8 b1 = *(const half8*)(qr + h * 64 + 32 + (g << 3));
        f32x4 acc = {0.f, 0.f, 0.f, 0.f};
        acc = __builtin_amdgcn_mfma_f32_16x16x32_f16(a0, b0, acc, 0, 0, 0);
        acc = __builtin_amdgcn_mfma_f32_16x16x32_f16(a1, b1, acc, 0, 0, 0);
        float e0 = (g < 3) ? __expf(acc[0]) : 0.f;
        float e1 = (g < 3) ? __expf(acc[1]) : 0.f;
        float e2 = (g < 3) ? __expf(acc[2]) : 0.f;
        float e3 = (g < 3) ? __expf(acc[3]) : 0.f;
        float s = e0 + e1 + e2 + e3;
        s += __shfl_xor(s, 16);
        s += __shfl_xor(s, 32);
        float inv = 1.0f / s;
        if (g < 3) {
          unsigned int w0 = f2h(e0 * inv) | ((unsigned int)f2h(e1 * inv) << 16);
          unsigned int w1 = f2h(e2 * inv) | ((unsigned int)f2h(e3 * inv) << 16);
          uint2v pk = {w0, w1};
          *(uint2v*)(Wt + (long)(v * 512 + t) * 96 + h * 12 + (g << 2)) = pk;
        }
      }
    }
  } else {
    int b2 = bx - 2048;
    int v = b2 >> 2, qt = b2 & 3;
    unsigned short* Zt = (unsigned short*)(ws + OFF_ZT);
    const unsigned short* vpr = VP + ((long)(v * 16 + l15) << 9);  // A row f=l15
#pragma unroll
    for (int h = 0; h < H_; ++h) {
      half8 a0 = *(const half8*)(vpr + h * 64 + (g << 3));
      half8 a1 = *(const half8*)(vpr + h * 64 + 32 + (g << 3));
#pragma unroll
      for (int mf = 0; mf < 2; ++mf) {
        int n = (qt << 7) + (wid << 5) + (mf << 4) + l15;
        const unsigned short* wor = WOT + ((long)n << 9);
        half8 b0 = *(const half8*)(wor + h * 64 + (g << 3));
        half8 b1 = *(const half8*)(wor + h * 64 + 32 + (g << 3));
        f32x4 acc = {0.f, 0.f, 0.f, 0.f};
        acc = __builtin_amdgcn_mfma_f32_16x16x32_f16(a0, b0, acc, 0, 0, 0);
        acc = __builtin_amdgcn_mfma_f32_16x16x32_f16(a1, b1, acc, 0, 0, 0);
        if (g < 3) {
          unsigned int w0 = f2h(acc[0]) | ((unsigned int)f2h(acc[1]) << 16);
          unsigned int w1 = f2h(acc[2]) | ((unsigned int)f2h(acc[3]) << 16);
          uint2v pk = {w0, w1};
          *(uint2v*)(Zt + (long)(v * 512 + n) * 96 + h * 12 + (g << 2)) = pk;
        }
      }
    }
  }
}

// ---------------------------------------------------------------------------
// K7: out[v][t][n] = sum_hf Wt[v][t][hf] * Zt[v][n][hf] + bo[n].
// NO LDS, NO barriers: fragments loaded directly from global (Wt/Zt rows are
// 192B-contiguous; L2/L3-resident). 24 independent dwordx4 loads + 48 MFMA.
// OPERAND SWAP vs round-5: A=Z-frag (n-side), B=W-frag (t-side) so C-layout
// gives each lane 4 CONSECUTIVE n -> float4 stores (16 per lane, was 64
// scalar dwords). Block = (v, tt, nt), 4 waves (2x2 of 64t x 64n).
// XCD swizzle: 8192 % 8 == 0 -> bijective; 16 blocks of a v share one L2.
// ---------------------------------------------------------------------------
__global__ __launch_bounds__(256, 4) void k7_gemm(char* ws, const float* __restrict__ bo,
                                                  float* __restrict__ outp) {
  int bx = blockIdx.x, tid = threadIdx.x;
  int bsw = (bx & 7) * 1024 + (bx >> 3);    // XCD-contiguous remap
  int v = bsw >> 4, tt = (bsw >> 2) & 3, nt = bsw & 3;
  const unsigned short* Wt = (const unsigned short*)(ws + OFF_WT);
  const unsigned short* Zt = (const unsigned short*)(ws + OFF_ZT);
  int lane = tid & 63, wid = tid >> 6;
  int l15 = lane & 15, g = lane >> 4;
  int mw = (wid >> 1) << 6, nw = (wid & 1) << 6;  // t-offset, n-offset of wave

  const unsigned short* Zb = Zt + (long)(v * 512 + (nt << 7) + nw) * 96;
  const unsigned short* Wb = Wt + (long)(v * 512 + (tt << 7) + mw) * 96;

  f32x4 acc[4][4];  // [i: n-frag][j: t-frag]
#pragma unroll
  for (int i = 0; i < 4; i++)
#pragma unroll
    for (int j = 0; j < 4; j++) acc[i][j] = (f32x4){0.f, 0.f, 0.f, 0.f};

#pragma unroll
  for (int ks = 0; ks < 3; ++ks) {
    half8 zf[4], wf[4];
#pragma unroll
    for (int i = 0; i < 4; i++)
      zf[i] = *(const half8*)(Zb + (long)(i * 16 + l15) * 96 + ks * 32 + (g << 3));
#pragma unroll
    for (int j = 0; j < 4; j++)
      wf[j] = *(const half8*)(Wb + (long)(j * 16 + l15) * 96 + ks * 32 + (g << 3));
#pragma unroll
    for (int i = 0; i < 4; i++)
#pragma unroll
      for (int j = 0; j < 4; j++)
        acc[i][j] = __builtin_amdgcn_mfma_f32_16x16x32_f16(zf[i], wf[j], acc[i][j], 0, 0, 0);
  }

#pragma unroll
  for (int i = 0; i < 4; i++) {
    int n = (nt << 7) + nw + i * 16 + (g << 2);
    float4 b4 = *(const float4*)(bo + n);
#pragma unroll
    for (int j = 0; j < 4; j++) {
      int t = (tt << 7) + mw + j * 16 + l15;
      float4 o;
      o.x = acc[i][j][0] + b4.x;
      o.y = acc[i][j][1] + b4.y;
      o.z = acc[i][j][2] + b4.z;
      o.w = acc[i][j][3] + b4.w;
      *(float4*)(outp + ((long)(v * 512 + t) << 9) + n) = o;
    }
  }
}

extern "C" void kernel_launch(void* const* d_in, const int* in_sizes, int n_in,
                              void* d_out, int out_size, void* d_ws, size_t ws_size,
                              hipStream_t stream) {
  const float* text  = (const float*)d_in[0];
  const float* video = (const float*)d_in[1];
  const float* Wq = (const float*)d_in[2];
  const float* bq = (const float*)d_in[3];
  const float* Wk = (const float*)d_in[4];
  const float* bk = (const float*)d_in[5];
  const float* Wv = (const float*)d_in[6];
  const float* bv = (const float*)d_in[7];
  const float* Wo = (const float*)d_in[8];
  const float* bo = (const float*)d_in[9];
  char* ws = (char*)d_ws;
  float* out = (float*)d_out;

  k0_prep<<<dim3(2432), dim3(256), 0, stream>>>(text, video, Wq, Wk, Wv, Wo, ws);
  k1_proj<<<dim3(528), dim3(256), 0, stream>>>(ws, bq, bk, bv);
  k6_pz<<<dim3(4096), dim3(256), 0, stream>>>(ws);
  k7_gemm<<<dim3(8192), dim3(256), 0, stream>>>(ws, bo, out);
}

// Round 7
// 704.237 us; speedup vs baseline: 1.2535x; 1.1892x over previous
//
#include <hip/hip_runtime.h>
#include <stdint.h>

// Problem constants
#define T_  512
#define V_  512
#define F_  12
#define FP_ 16
#define D_  512
#define H_  8
#define HF_ 96

using half8  = __attribute__((ext_vector_type(8))) _Float16;
using f32x4  = __attribute__((ext_vector_type(4))) float;
using uint4v = __attribute__((ext_vector_type(4))) unsigned int;
using uint2v = __attribute__((ext_vector_type(2))) unsigned int;

// Workspace layout (bytes). Used total = ~128 MB
#define OFF_TB   (0L)                       // text fp16      [512][512] row-major
#define OFF_VB   (524288L)                  // video fp16     [512][16][512] row-major (F padded, zeros)
#define OFF_WQT  (OFF_VB  + 8388608L)       // WqT fp16 row-major [n][k]
#define OFF_WKT  (OFF_WQT + 524288L)
#define OFF_WVT  (OFF_WKT + 524288L)
#define OFF_WOT  (OFF_WVT + 524288L)        // WoT fp16 FRAG-LINEAR fl(n,d,64)
#define OFF_QB   (OFF_WOT + 524288L)        // q fp16 (x0.125) FRAG-LINEAR fl(t,d,64)
#define OFF_KP   (OFF_QB  + 524288L)        // kproj fp16 FRAG-LINEAR fl(v*16+f,d,64)
#define OFF_VP   (OFF_KP  + 8388608L)       // vproj fp16 FRAG-LINEAR
#define OFF_ZT   (OFF_VP  + 8388608L)       // Zt fp16 per-v FRAG-LINEAR v*49152 + fl(n,k,12)
#define OFF_WT   (OFF_ZT  + 50331648L)      // Wt fp16 per-v FRAG-LINEAR v*49152 + fl(t,k,12)

// Fragment-linear addressing (in HALF elements):
// [row/16][col/8][row%16][8]  ->  a wave's MFMA fragment (16 rows = l15,
// 8 halves per lane, 4 k-groups = g) is 1024 CONTIGUOUS bytes.
__device__ __forceinline__ long flh(int row, int col, int ncolg) {
  return ((long)((row >> 4) * ncolg + (col >> 3)) << 7) + ((row & 15) << 3) + (col & 7);
}

__device__ __forceinline__ unsigned short f2h(float x) {
  _Float16 h = (_Float16)x;
  return __builtin_bit_cast(unsigned short, h);
}

__device__ __forceinline__ void cvt8_store(float4 a, float4 b, unsigned short* dst) {
  unsigned int w0 = f2h(a.x) | ((unsigned int)f2h(a.y) << 16);
  unsigned int w1 = f2h(a.z) | ((unsigned int)f2h(a.w) << 16);
  unsigned int w2 = f2h(b.x) | ((unsigned int)f2h(b.y) << 16);
  unsigned int w3 = f2h(b.z) | ((unsigned int)f2h(b.w) << 16);
  uint4v v = {w0, w1, w2, w3};
  *(uint4v*)dst = v;
}

// ---------------------------------------------------------------------------
// K0: convert inputs to fp16; build transposed fp16 weight copies.
// WQT/WKT/WVT row-major (K1 stages them); WOT -> frag-linear (K6 reads frags).
// ---------------------------------------------------------------------------
__global__ __launch_bounds__(256) void k0_prep(
    const float* __restrict__ text, const float* __restrict__ video,
    const float* __restrict__ Wq, const float* __restrict__ Wk,
    const float* __restrict__ Wv, const float* __restrict__ Wo, char* ws) {
  __shared__ unsigned short tl[64][72];
  int bx = blockIdx.x, tid = threadIdx.x;
  if (bx < 128) {
    unsigned short* tb = (unsigned short*)(ws + OFF_TB);
    long i = ((long)bx * 256 + tid) * 8;
    float4 a = *(const float4*)(text + i);
    float4 b = *(const float4*)(text + i + 4);
    cvt8_store(a, b, tb + i);
  } else if (bx < 2176) {
    unsigned short* vb = (unsigned short*)(ws + OFF_VB);
    long j = ((long)(bx - 128) * 256 + tid) * 8;  // elem idx in [512][16][512]
    int row = (int)(j >> 9);
    int c   = (int)(j & 511);
    int f = row & 15, v = row >> 4;
    if (f < F_) {
      const float* src = video + ((long)(v * F_ + f) << 9) + c;
      float4 a = *(const float4*)src;
      float4 b = *(const float4*)(src + 4);
      cvt8_store(a, b, vb + j);
    } else {
      uint4v z = {0, 0, 0, 0};
      *(uint4v*)(vb + j) = z;
    }
  } else {
    int tix = bx - 2176;
    int w = tix >> 6, tile = tix & 63;
    const float* W = (w == 0) ? Wq : (w == 1) ? Wk : (w == 2) ? Wv : Wo;
    unsigned short* WT = (unsigned short*)(ws +
        ((w == 0) ? OFF_WQT : (w == 1) ? OFF_WKT : (w == 2) ? OFF_WVT : OFF_WOT));
    int r0 = (tile >> 3) * 64, c0 = (tile & 7) * 64;
    int rr = tid >> 4, cc = (tid & 15) * 4;
#pragma unroll
    for (int j2 = 0; j2 < 4; ++j2) {
      int r = rr + j2 * 16;
      float4 a = *(const float4*)(W + (long)(r0 + r) * 512 + c0 + cc);
      tl[cc + 0][r] = f2h(a.x);
      tl[cc + 1][r] = f2h(a.y);
      tl[cc + 2][r] = f2h(a.z);
      tl[cc + 3][r] = f2h(a.w);
    }
    __syncthreads();
    // 256 threads x 16 ushorts = the full 64x64 tile in ONE pass.
    int row_l = tid >> 2, u = (tid & 3) * 16;
    uint4v x0 = *(uint4v*)&tl[row_l][u];
    uint4v x1 = *(uint4v*)&tl[row_l][u + 8];
    int n = c0 + row_l;   // dest row (output-dim)
    int d0 = r0 + u;      // dest col (k-dim), 16-aligned
    if (w == 3) {
      // frag-linear: each 8-half group is one 16B colgrp slot
      *(uint4v*)(WT + flh(n, d0, 64))     = x0;
      *(uint4v*)(WT + flh(n, d0 + 8, 64)) = x1;
    } else {
      unsigned short* dst = WT + (long)n * 512 + d0;
      *(uint4v*)dst = x0;
      *(uint4v*)(dst + 8) = x1;
    }
  }
}

// ---------------------------------------------------------------------------
// K1: fused projection GEMMs (fp16 MFMA).  out = (A @ W + b) * scale
// Epilogue now writes FRAG-LINEAR layouts (QB/KP/VP).
// ---------------------------------------------------------------------------
__global__ __launch_bounds__(256) void k1_proj(
    char* ws, const float* __restrict__ bq, const float* __restrict__ bk,
    const float* __restrict__ bv) {
  __shared__ unsigned short As[128 * 72];
  __shared__ unsigned short Bs[128 * 72];
  int bx = blockIdx.x, tid = threadIdx.x;
  int nt = bx & 3, mt = bx >> 2;
  const unsigned short* A;
  const unsigned short* BT;
  const float* bias;
  float scale;
  unsigned short* out;
  int m0;
  if (mt < 4) {
    A = (const unsigned short*)(ws + OFF_TB);
    BT = (const unsigned short*)(ws + OFF_WQT);
    bias = bq; scale = 0.125f;
    out = (unsigned short*)(ws + OFF_QB);
    m0 = mt << 7;
  } else if (mt < 68) {
    A = (const unsigned short*)(ws + OFF_VB);
    BT = (const unsigned short*)(ws + OFF_WKT);
    bias = bk; scale = 1.0f;
    out = (unsigned short*)(ws + OFF_KP);
    m0 = (mt - 4) << 7;
  } else {
    A = (const unsigned short*)(ws + OFF_VB);
    BT = (const unsigned short*)(ws + OFF_WVT);
    bias = bv; scale = 1.0f;
    out = (unsigned short*)(ws + OFF_VP);
    m0 = (mt - 68) << 7;
  }
  int n0 = nt << 7;
  int lane = tid & 63, wid = tid >> 6;
  int mw = (wid >> 1) << 6, nw = (wid & 1) << 6;
  int l15 = lane & 15, g = lane >> 4;
  f32x4 acc[4][4];
#pragma unroll
  for (int i = 0; i < 4; i++)
#pragma unroll
    for (int j = 0; j < 4; j++) acc[i][j] = (f32x4){0.f, 0.f, 0.f, 0.f};

  for (int ks = 0; ks < 8; ++ks) {
    __syncthreads();
    // stage A,B [128][64] -> padded [128][72]
#pragma unroll
    for (int j = 0; j < 4; ++j) {
      int flat = (j * 256 + tid) * 8;
      int row = flat >> 6, col = flat & 63;
      uint4v va = *(const uint4v*)(A + (long)(m0 + row) * 512 + ks * 64 + col);
      uint4v vb = *(const uint4v*)(BT + (long)(n0 + row) * 512 + ks * 64 + col);
      *(uint4v*)(As + row * 72 + col) = va;
      *(uint4v*)(Bs + row * 72 + col) = vb;
    }
    __syncthreads();
#pragma unroll
    for (int k2 = 0; k2 < 2; ++k2) {
      half8 a[4], b[4];
#pragma unroll
      for (int i = 0; i < 4; i++) {
        a[i] = *(const half8*)(As + (mw + i * 16 + l15) * 72 + k2 * 32 + (g << 3));
        b[i] = *(const half8*)(Bs + (nw + i * 16 + l15) * 72 + k2 * 32 + (g << 3));
      }
#pragma unroll
      for (int i = 0; i < 4; i++)
#pragma unroll
        for (int j = 0; j < 4; j++)
          acc[i][j] = __builtin_amdgcn_mfma_f32_16x16x32_f16(a[i], b[j], acc[i][j], 0, 0, 0);
    }
  }
  // epilogue: frag-linear scatter (same store count as before, fl addressing)
#pragma unroll
  for (int j = 0; j < 4; j++) {
    int n = n0 + nw + j * 16 + l15;
    float bsv = bias[n];
#pragma unroll
    for (int i = 0; i < 4; i++) {
      int rbase = m0 + mw + i * 16 + (g << 2);
#pragma unroll
      for (int r = 0; r < 4; r++) {
        float x = (acc[i][j][r] + bsv) * scale;
        out[flh(rbase + r, n, 64)] = f2h(x);
      }
    }
  }
}

// ---------------------------------------------------------------------------
// K6: P (softmax weights) and Z (Wo-contraction) to workspace, frag-linear.
// NO LDS, NO barriers. All fragment loads are 1024B-contiguous wave loads
// (frag-linear inputs); stores are 2-3 contiguous segments.
// grid = 4096: bx<2048 -> P (v, 128 t-rows); else Z (v, 128 n-rows).
//   P: D[f][t] = mfma(A=kproj f-frag, B=q t-frag); softmax over f in-lane
//      (3 adds + 2 shfl_xor); no max-pass (|logit| <~ 6).
//   Z: D[f][n] = mfma(A=vproj f-frag, B=WoT n-frag).
// Lane(l15,g) reg r holds f=g*4+r; g==3 (padded f=12..15) never stored.
// k-index in Wt/Zt is h*12+f for BOTH (consistent contraction order).
// ---------------------------------------------------------------------------
__global__ __launch_bounds__(256) void k6_pz(char* ws) {
  int bx = blockIdx.x, tid = threadIdx.x;
  int lane = tid & 63, wid = tid >> 6;
  int l15 = lane & 15, g = lane >> 4;
  int lo = l15 << 3;

  if (bx < 2048) {
    int v = bx >> 2, qt = bx & 3;
    const unsigned short* KPv = (const unsigned short*)(ws + OFF_KP) + ((long)v << 13);
    const unsigned short* QB  = (const unsigned short*)(ws + OFF_QB);
    unsigned short* Wtv = (unsigned short*)(ws + OFF_WT) + (long)v * 49152;
#pragma unroll
    for (int h = 0; h < H_; ++h) {
      half8 a0 = *(const half8*)(KPv + (((h << 3) + g) << 7) + lo);
      half8 a1 = *(const half8*)(KPv + (((h << 3) + 4 + g) << 7) + lo);
#pragma unroll
      for (int ti = 0; ti < 2; ++ti) {
        int tb = (qt << 7) + (wid << 5) + (ti << 4);  // 16-aligned t base
        int trg = tb >> 4;
        const unsigned short* qrg = QB + ((long)trg << 13);  // trg*64*128
        half8 b0 = *(const half8*)(qrg + (((h << 3) + g) << 7) + lo);
        half8 b1 = *(const half8*)(qrg + (((h << 3) + 4 + g) << 7) + lo);
        f32x4 acc = {0.f, 0.f, 0.f, 0.f};
        acc = __builtin_amdgcn_mfma_f32_16x16x32_f16(a0, b0, acc, 0, 0, 0);
        acc = __builtin_amdgcn_mfma_f32_16x16x32_f16(a1, b1, acc, 0, 0, 0);
        float e0 = (g < 3) ? __expf(acc[0]) : 0.f;
        float e1 = (g < 3) ? __expf(acc[1]) : 0.f;
        float e2 = (g < 3) ? __expf(acc[2]) : 0.f;
        float e3 = (g < 3) ? __expf(acc[3]) : 0.f;
        float s = e0 + e1 + e2 + e3;
        s += __shfl_xor(s, 16);
        s += __shfl_xor(s, 32);
        float inv = 1.0f / s;
        if (g < 3) {
          unsigned int w0 = f2h(e0 * inv) | ((unsigned int)f2h(e1 * inv) << 16);
          unsigned int w1 = f2h(e2 * inv) | ((unsigned int)f2h(e3 * inv) << 16);
          uint2v pk = {w0, w1};
          int k0 = h * 12 + (g << 2);
          long ad = ((long)(trg * 12 + (k0 >> 3)) << 7) + lo + (k0 & 7);
          *(uint2v*)(Wtv + ad) = pk;
        }
      }
    }
  } else {
    int b2 = bx - 2048;
    int v = b2 >> 2, qt = b2 & 3;
    const unsigned short* VPv = (const unsigned short*)(ws + OFF_VP) + ((long)v << 13);
    const unsigned short* WOT = (const unsigned short*)(ws + OFF_WOT);
    unsigned short* Ztv = (unsigned short*)(ws + OFF_ZT) + (long)v * 49152;
#pragma unroll
    for (int h = 0; h < H_; ++h) {
      half8 a0 = *(const half8*)(VPv + (((h << 3) + g) << 7) + lo);
      half8 a1 = *(const half8*)(VPv + (((h << 3) + 4 + g) << 7) + lo);
#pragma unroll
      for (int mf = 0; mf < 2; ++mf) {
        int nb = (qt << 7) + (wid << 5) + (mf << 4);
        int nrg = nb >> 4;
        const unsigned short* wrg = WOT + ((long)nrg << 13);
        half8 b0 = *(const half8*)(wrg + (((h << 3) + g) << 7) + lo);
        half8 b1 = *(const half8*)(wrg + (((h << 3) + 4 + g) << 7) + lo);
        f32x4 acc = {0.f, 0.f, 0.f, 0.f};
        acc = __builtin_amdgcn_mfma_f32_16x16x32_f16(a0, b0, acc, 0, 0, 0);
        acc = __builtin_amdgcn_mfma_f32_16x16x32_f16(a1, b1, acc, 0, 0, 0);
        if (g < 3) {
          unsigned int w0 = f2h(acc[0]) | ((unsigned int)f2h(acc[1]) << 16);
          unsigned int w1 = f2h(acc[2]) | ((unsigned int)f2h(acc[3]) << 16);
          uint2v pk = {w0, w1};
          int k0 = h * 12 + (g << 2);
          long ad = ((long)(nrg * 12 + (k0 >> 3)) << 7) + lo + (k0 & 7);
          *(uint2v*)(Ztv + ad) = pk;
        }
      }
    }
  }
}

// ---------------------------------------------------------------------------
// K7: out[v][t][n] = sum_k Wt[v][t][k] * Zt[v][n][k] + bo[n].
// NO LDS, NO barriers. Frag-linear Wt/Zt -> every fragment load is ONE
// 1024B-contiguous wave load (24 total). A=Z-frag (n-side), B=W-frag (t-side)
// -> lane holds 4 consecutive n -> float4 stores. Block = (v, tt, nt),
// 4 waves (2x2 of 64t x 64n). XCD-bijective swizzle (8192 % 8 == 0).
// ---------------------------------------------------------------------------
__global__ __launch_bounds__(256) void k7_gemm(char* ws, const float* __restrict__ bo,
                                               float* __restrict__ outp) {
  int bx = blockIdx.x, tid = threadIdx.x;
  int bsw = (bx & 7) * 1024 + (bx >> 3);    // XCD-contiguous remap
  int v = bsw >> 4, tt = (bsw >> 2) & 3, nt = bsw & 3;
  const unsigned short* Wtv = (const unsigned short*)(ws + OFF_WT) + (long)v * 49152;
  const unsigned short* Ztv = (const unsigned short*)(ws + OFF_ZT) + (long)v * 49152;
  int lane = tid & 63, wid = tid >> 6;
  int l15 = lane & 15, g = lane >> 4;
  int lo = l15 << 3;
  int mw = (wid >> 1) << 6, nw = (wid & 1) << 6;  // t-offset, n-offset of wave
  int trg0 = ((tt << 7) + mw) >> 4;
  int nrg0 = ((nt << 7) + nw) >> 4;

  f32x4 acc[4][4];  // [i: n-frag][j: t-frag]
#pragma unroll
  for (int i = 0; i < 4; i++)
#pragma unroll
    for (int j = 0; j < 4; j++) acc[i][j] = (f32x4){0.f, 0.f, 0.f, 0.f};

#pragma unroll
  for (int ks = 0; ks < 3; ++ks) {
    half8 zf[4], wf[4];
#pragma unroll
    for (int i = 0; i < 4; i++)
      zf[i] = *(const half8*)(Ztv + ((long)((nrg0 + i) * 12 + (ks << 2) + g) << 7) + lo);
#pragma unroll
    for (int j = 0; j < 4; j++)
      wf[j] = *(const half8*)(Wtv + ((long)((trg0 + j) * 12 + (ks << 2) + g) << 7) + lo);
#pragma unroll
    for (int i = 0; i < 4; i++)
#pragma unroll
      for (int j = 0; j < 4; j++)
        acc[i][j] = __builtin_amdgcn_mfma_f32_16x16x32_f16(zf[i], wf[j], acc[i][j], 0, 0, 0);
  }

#pragma unroll
  for (int i = 0; i < 4; i++) {
    int n = (nt << 7) + nw + i * 16 + (g << 2);
    float4 b4 = *(const float4*)(bo + n);
#pragma unroll
    for (int j = 0; j < 4; j++) {
      int t = (tt << 7) + mw + j * 16 + l15;
      float4 o;
      o.x = acc[i][j][0] + b4.x;
      o.y = acc[i][j][1] + b4.y;
      o.z = acc[i][j][2] + b4.z;
      o.w = acc[i][j][3] + b4.w;
      *(float4*)(outp + ((long)(v * 512 + t) << 9) + n) = o;
    }
  }
}

extern "C" void kernel_launch(void* const* d_in, const int* in_sizes, int n_in,
                              void* d_out, int out_size, void* d_ws, size_t ws_size,
                              hipStream_t stream) {
  const float* text  = (const float*)d_in[0];
  const float* video = (const float*)d_in[1];
  const float* Wq = (const float*)d_in[2];
  const float* bq = (const float*)d_in[3];
  const float* Wk = (const float*)d_in[4];
  const float* bk = (const float*)d_in[5];
  const float* Wv = (const float*)d_in[6];
  const float* bv = (const float*)d_in[7];
  const float* Wo = (const float*)d_in[8];
  const float* bo = (const float*)d_in[9];
  char* ws = (char*)d_ws;
  float* out = (float*)d_out;

  k0_prep<<<dim3(2432), dim3(256), 0, stream>>>(text, video, Wq, Wk, Wv, Wo, ws);
  k1_proj<<<dim3(528), dim3(256), 0, stream>>>(ws, bq, bk, bv);
  k6_pz<<<dim3(4096), dim3(256), 0, stream>>>(ws);
  k7_gemm<<<dim3(8192), dim3(256), 0, stream>>>(ws, bo, out);
}